// Round 8
// baseline (396.084 us; speedup 1.0000x reference)
//
#include <hip/hip_runtime.h>
#include <math.h>

// Problem constants (reference setup_inputs: B=16, L=512, timesteps=20).
#define BB 16
#define LL 512
#define TS 20

// ---------------- row-panel cooperative path (round 8) ----------------
#define NPANEL 16                 // row-panels per batch (32 rows each)
#define PROWS 32
#define NBLK2 (BB * NPANEL)       // 256 blocks, 1/CU
#define CROWS (BB * LL)           // floats per cbuf step slab
#define UTST 36                   // ut row stride (16B-aligned, bank-spread)
#define UTFLOATS (512 * UTST)     // 18432
#define W2ST 516                  // w2sh row stride
#define W2FLOATS (32 * W2ST)      // 16512
#define SM2_FLOATS (UTFLOATS + W2FLOATS + 512)
#define SM2_BYTES (SM2_FLOATS * 4)  // 141,824 B < 160 KB

// ---------------- legacy pair-tile path (round-5, proven 395us) -------
#define TT 64
#define NT (LL / TT)
#define NPAIR (NT * (NT + 1) / 2)
#define NUNIT 32
#define NBLK (BB * NUNIT)
#define BLL (BB * LL * LL)
#define NROW (BB * LL)
#define RSPSTEP (BB * NT * LL)

#define S_CONST 2.19722457733621938f  // log(9)

typedef float float4n __attribute__((ext_vector_type(4)));

__device__ __forceinline__ float sgm(float v) { return 1.0f / (1.0f + __expf(-v)); }
__device__ __forceinline__ float ahat_of(float up) {
  return sgm(up) * sgm(2.0f * (up - S_CONST));
}

__device__ __forceinline__ void st_agent(float* p, float v) {
  __hip_atomic_store(p, v, __ATOMIC_RELAXED, __HIP_MEMORY_SCOPE_AGENT);
}
__device__ __forceinline__ float ld_agent(const float* p) {
  return __hip_atomic_load(p, __ATOMIC_RELAXED, __HIP_MEMORY_SCOPE_AGENT);
}

// lgkm-only barrier (global stores stay in flight across it)
__device__ __forceinline__ void bar_lds() {
  asm volatile("s_waitcnt lgkmcnt(0)" ::: "memory");
  __builtin_amdgcn_s_barrier();
  asm volatile("" ::: "memory");
}

// =====================================================================
// k_panel (round 8): 256 blocks; block = (batch b, row-panel p) owning
// rows [p*32, p*32+32) x all 512 cols. Each thread carries BOTH halves
// of its 64 element-pairs: av = a_ij and avT = a_ji (the transpose
// panel), initialized from the staged u'^T. Since m, w, and c_i+c_j are
// symmetric, ONE factor F = 1 - alpha*m*(w+ci+cj) updates both halves.
// Consequences:
//   rowsum_i = sum_j (an^2 + anT^2)*mh   -- FULLY LOCAL (fixes the
//     round-7 bug where the transpose half of the rowsum was missing)
//   out_ij = the same value              -- computed in registers; no
//     cross-block v exchange, no vbufT, no flags.
// Per-step inter-block traffic: c only (publish 32 biased floats, poll
// 512 branchless, data-as-flag). Chain/step = 1 LLC RT + phase1 + 2
// lgkm-only barriers; the 16.8 MB/step out burst is NT-stored from
// registers and drains off-chain.
// =====================================================================
__global__ __launch_bounds__(256, 1) void k_panel(const float* __restrict__ u,
                                                  const float* __restrict__ x,
                                                  float* __restrict__ cbuf,  // [TS+1][BB][512] biased 2c+1, zeroed
                                                  float* __restrict__ out) {
  extern __shared__ float smem[];
  float* ut = smem;                          // [512][36] u'^T panel (init only)
  float* w2sh = smem + UTFLOATS;             // [32][516] per-row 2w; init: xt [512][4]
  float* carr = smem + UTFLOATS + W2FLOATS;  // [512] 2c values for current step

  int b = blockIdx.x / NPANEL;
  int panel = blockIdx.x % NPANEL;
  int P0 = panel * PROWS;

  int tid = threadIdx.x;
  int tx = tid & 7;   // column-chunk lane (8 per row)
  int ty = tid >> 3;  // local row 0..31
  int gi = P0 + ty;   // global row of this thread

  float av[16][4], avT[16][4], mh[16][4];

  // ---- init 1: x factors -> xt (in w2sh region; dead after init 2) ----
  {
    int j1 = tid, j2 = tid + 256;
    const float* xp1 = x + ((size_t)b * LL + j1) * 4;
    const float* xp2 = x + ((size_t)b * LL + j2) * 4;
    float A1 = xp1[0], U1 = xp1[1], C1v = xp1[2], G1 = xp1[3];
    float A2 = xp2[0], U2 = xp2[1], C2v = xp2[2], G2 = xp2[3];
    w2sh[j1 * 4 + 0] = U1; w2sh[j1 * 4 + 1] = A1 + G1;
    w2sh[j1 * 4 + 2] = G1; w2sh[j1 * 4 + 3] = C1v + U1;
    w2sh[j2 * 4 + 0] = U2; w2sh[j2 * 4 + 1] = A2 + G2;
    w2sh[j2 * 4 + 2] = G2; w2sh[j2 * 4 + 3] = C2v + U2;
  }
  float4 xr = *reinterpret_cast<const float4*>(x + ((size_t)b * LL + gi) * 4);
  __syncthreads();

  // ---- init 2: mh = 0.5*m into regs ----
#pragma unroll
  for (int k = 0; k < 16; ++k) {
#pragma unroll
    for (int q = 0; q < 4; ++q) {
      int j = k * 32 + tx * 4 + q;
      int d = gi - j; d = d < 0 ? -d : d;
      float4n xt4 = *reinterpret_cast<float4n*>(w2sh + j * 4);
      float mm = xr.x * xt4[0] + xr.y * xt4[1] + xr.z * xt4[2] + xr.w * xt4[3];
      mh[k][q] = (d <= 3) ? 0.0f : 0.5f * mm;
    }
  }
  __syncthreads();

  // ---- init 3: stage u'(j, panel-cols) transposed into ut ----
  // ut[j][c] = u'[j][P0+c] at ut[j*36 + c]; coalesced 128B global loads.
#pragma unroll 4
  for (int h = 0; h < 16; ++h) {
    int j = ty + 32 * h;
    float4 u4 = *reinterpret_cast<const float4*>(u + ((size_t)b * LL + j) * LL + P0 + tx * 4);
    float uu[4] = {u4.x, u4.y, u4.z, u4.w};
    float4n st;
#pragma unroll
    for (int q = 0; q < 4; ++q) st[q] = sgm(2.0f * (uu[q] - S_CONST)) * uu[q];
    *reinterpret_cast<float4n*>(ut + j * UTST + tx * 4) = st;
  }
  __syncthreads();

  // ---- init 4: row pass -> w2 (LDS, own row), av, avT, rowsum0; c(0) ----
  float rs0 = 0.0f;
#pragma unroll
  for (int k = 0; k < 16; ++k) {
    float4 u4 = *reinterpret_cast<const float4*>(u + ((size_t)b * LL + gi) * LL + k * 32 + tx * 4);
    float uu[4] = {u4.x, u4.y, u4.z, u4.w};
#pragma unroll
    for (int q = 0; q < 4; ++q) {
      int j = k * 32 + tx * 4 + q;
      float up = sgm(2.0f * (uu[q] - S_CONST)) * uu[q];
      float upT = ut[j * UTST + ty];
      w2sh[ty * W2ST + j] = -(up + upT);  // 2*w (own row; read back by same thread)
      float a0 = ahat_of(up);
      float aT0 = ahat_of(upT);
      av[k][q] = a0;
      avT[k][q] = aT0;
      rs0 += (a0 * a0 + aT0 * aT0) * mh[k][q];
    }
  }
  rs0 += __shfl_xor(rs0, 1); rs0 += __shfl_xor(rs0, 2); rs0 += __shfl_xor(rs0, 4);
  float dv0 = rs0 - 1.0f;
  float lmbd = dv0 > 0.0f ? dv0 : 0.0f;
  if (tx == 0) st_agent(&cbuf[(size_t)b * LL + gi], 2.0f * (lmbd * sgm(2.0f * dv0)) + 1.0f);

  // ---- step loop ----
  float alpha = 0.01f;
  float beta = 0.1f;

  for (int t = 0; t < TS; ++t) {
    // A: wave 0 polls all 512 biased c values for step t (branchless)
    if (tid < 64) {
      const float* cp = cbuf + (size_t)t * CROWS + (size_t)b * LL + tid;
      float v0, v1, v2, v3, v4, v5, v6, v7;
      for (;;) {
        v0 = ld_agent(cp + 0 * 64); v1 = ld_agent(cp + 1 * 64);
        v2 = ld_agent(cp + 2 * 64); v3 = ld_agent(cp + 3 * 64);
        v4 = ld_agent(cp + 4 * 64); v5 = ld_agent(cp + 5 * 64);
        v6 = ld_agent(cp + 6 * 64); v7 = ld_agent(cp + 7 * 64);
        bool ok = (v0 != 0.0f) & (v1 != 0.0f) & (v2 != 0.0f) & (v3 != 0.0f) &
                  (v4 != 0.0f) & (v5 != 0.0f) & (v6 != 0.0f) & (v7 != 0.0f);
        if (__all(ok)) break;
        __builtin_amdgcn_s_sleep(1);
        asm volatile("" ::: "memory");
      }
      carr[tid + 0 * 64] = v0 - 1.0f; carr[tid + 1 * 64] = v1 - 1.0f;
      carr[tid + 2 * 64] = v2 - 1.0f; carr[tid + 3 * 64] = v3 - 1.0f;
      carr[tid + 4 * 64] = v4 - 1.0f; carr[tid + 5 * 64] = v5 - 1.0f;
      carr[tid + 6 * 64] = v6 - 1.0f; carr[tid + 7 * 64] = v7 - 1.0f;
    }
    bar_lds();  // BAR_A: carr(t) visible to all

    // C: phase1 — one factor F per element-pair updates BOTH av and avT;
    // o = (an^2 + anT^2)*mh is simultaneously the out value AND the
    // rowsum contribution. NT-store out inline (off-chain drain).
    float thr = alpha * 0.99f;
    float crow = carr[gi];
    float rsacc = 0.0f;
    float* op = out + ((size_t)t * BB + b) * LL * LL + (size_t)gi * LL;
#pragma unroll
    for (int k = 0; k < 16; ++k) {
      float4n w4 = *reinterpret_cast<float4n*>(w2sh + ty * W2ST + k * 32 + tx * 4);
      float4n cc4 = *reinterpret_cast<float4n*>(carr + k * 32 + tx * 4);
      float4n o4;
#pragma unroll
      for (int q = 0; q < 4; ++q) {
        float m5 = mh[k][q];
        float s = w4[q] + crow + cc4[q];
        float F = fmaf(-alpha, m5 * s, 1.0f);
        float an = av[k][q] * F;
        an = fminf(fmaxf(fabsf(an) - thr, 0.0f), 1.0f);
        float anT = avT[k][q] * F;
        anT = fminf(fmaxf(fabsf(anT) - thr, 0.0f), 1.0f);
        av[k][q] = an;
        avT[k][q] = anT;
        float o = fmaf(an, an, anT * anT) * m5;
        o4[q] = o;
        rsacc += o;
      }
      __builtin_nontemporal_store(o4, reinterpret_cast<float4n*>(op + k * 32 + tx * 4));
    }

    // D: local FULL rowsum -> lambda -> publish c(t+1)
    rsacc += __shfl_xor(rsacc, 1); rsacc += __shfl_xor(rsacc, 2); rsacc += __shfl_xor(rsacc, 4);
    {
      float dv = rsacc - 1.0f;
      float rel = dv > 0.0f ? dv : 0.0f;
      lmbd = lmbd + beta * rel;
      if (t < TS - 1 && tx == 0) {
        st_agent(&cbuf[(size_t)(t + 1) * CROWS + (size_t)b * LL + gi],
                 2.0f * (lmbd * sgm(2.0f * dv)) + 1.0f);
      }
    }
    bar_lds();  // BAR_B: all carr(t) reads retired before next A overwrites

    beta *= 0.99f;
    alpha *= 0.99f;
  }
}

// =====================================================================
// FALLBACK 1: round-5 pair-tile cooperative kernel (proven, 395us).
// =====================================================================
__device__ __forceinline__ void decode_unit(int p, int& RI, int& RJ, bool& dg) {
  if (p < 28) {
    int base = 0, i = 0;
    while (p >= base + (NT - 1 - i)) { base += NT - 1 - i; ++i; }
    RI = i;
    RJ = i + 1 + (p - base);
    dg = false;
  } else {
    int g = p - 28;
    RI = 2 * g;
    RJ = 2 * g + 1;
    dg = true;
  }
}

__global__ __launch_bounds__(256, 2) void k_fused(const float* __restrict__ u,
                                                  const float* __restrict__ x,
                                                  float* __restrict__ rsp,
                                                  float* __restrict__ out) {
  __shared__ float t1[TT][TT + 1];
  __shared__ float t2[TT][TT + 1];
  __shared__ float colp1[16][TT];
  __shared__ float colp2[16][TT];
  __shared__ float rp1[TT];
  __shared__ float rp2[TT];
  __shared__ float xr[2][TT][4];
  __shared__ float xt[2][TT][4];
  __shared__ float cI[TT];
  __shared__ float cJ[TT];

  int b = blockIdx.x / NUNIT;
  int p = blockIdx.x % NUNIT;
  int RI, RJ;
  bool dg;
  decode_unit(p, RI, RJ, dg);
  int C1 = dg ? RI : RJ;
  int C2 = dg ? RJ : RI;

  int tid = threadIdx.x;
  int tx = tid & 15, ty = tid >> 4;

  if (tid < 128) {
    int which = tid >> 6;
    int r = tid & 63;
    int gi = (which ? RJ : RI) * TT + r;
    const float* xp = x + ((b * LL) + gi) * 4;
    float A = xp[0], U = xp[1], C = xp[2], G = xp[3];
    xr[which][r][0] = A; xr[which][r][1] = U; xr[which][r][2] = C; xr[which][r][3] = G;
    xt[which][r][0] = U; xt[which][r][1] = A + G; xt[which][r][2] = G; xt[which][r][3] = C + U;
  }

  int lrow = 0;
  if (tid < 128) {
    int which = tid >> 6;
    int r = tid & 63;
    lrow = (which ? RJ : RI) * TT + r;
  }
  float lmbd = 0.0f;

  float av1[4][4], av2[4][4];
  float wv1[4][4], wv2[4][4];
  float mv1[4][4], mv2[4][4];

  __syncthreads();

#pragma unroll
  for (int k = 0; k < 4; ++k) {
    int r = ty + 16 * k;
    {
      int i = RI * TT + r;
      int off = (b * LL + i) * LL + C1 * TT + 4 * tx;
      float4 u4 = *reinterpret_cast<const float4*>(u + off);
      float uu[4] = {u4.x, u4.y, u4.z, u4.w};
#pragma unroll
      for (int q = 0; q < 4; ++q) {
        float up = sgm(2.0f * (uu[q] - S_CONST)) * uu[q];
        t1[r][4 * tx + q] = up;
        av1[k][q] = ahat_of(up);
      }
    }
    {
      int i = RJ * TT + r;
      int off = (b * LL + i) * LL + C2 * TT + 4 * tx;
      float4 u4 = *reinterpret_cast<const float4*>(u + off);
      float uu[4] = {u4.x, u4.y, u4.z, u4.w};
#pragma unroll
      for (int q = 0; q < 4; ++q) {
        float up = sgm(2.0f * (uu[q] - S_CONST)) * uu[q];
        t2[r][4 * tx + q] = up;
        av2[k][q] = ahat_of(up);
      }
    }
  }
  __syncthreads();

  {
    float (*T1)[TT + 1] = dg ? t1 : t2;
    float (*T2)[TT + 1] = dg ? t2 : t1;
    float (*xc1)[4] = dg ? xt[0] : xt[1];
    float (*xc2)[4] = dg ? xt[1] : xt[0];
    float* rsp0 = rsp;

#pragma unroll
    for (int k = 0; k < 4; ++k) {
      int r = ty + 16 * k;
      {
        int i = RI * TT + r;
        float rs = 0.0f;
#pragma unroll
        for (int q = 0; q < 4; ++q) {
          int c = 4 * tx + q;
          int j = C1 * TT + c;
          float upT = T1[c][r];
          wv1[k][q] = -(t1[r][c] + upT);
          int d = i - j; d = d < 0 ? -d : d;
          float mm = (d <= 3) ? 0.0f
                              : xr[0][r][0] * xc1[c][0] + xr[0][r][1] * xc1[c][1] +
                                    xr[0][r][2] * xc1[c][2] + xr[0][r][3] * xc1[c][3];
          float mhq = 0.5f * mm;
          mv1[k][q] = mhq;
          float aT = ahat_of(upT);
          float a = av1[k][q];
          rs += (a * a + aT * aT) * mhq;
        }
        rs += __shfl_xor(rs, 1); rs += __shfl_xor(rs, 2);
        rs += __shfl_xor(rs, 4); rs += __shfl_xor(rs, 8);
        if (tx == 0) st_agent(&rsp0[(b * NT + C1) * LL + i], rs + 1.0f);
      }
      {
        int i = RJ * TT + r;
        float rs = 0.0f;
#pragma unroll
        for (int q = 0; q < 4; ++q) {
          int c = 4 * tx + q;
          int j = C2 * TT + c;
          float upT = T2[c][r];
          wv2[k][q] = -(t2[r][c] + upT);
          int d = i - j; d = d < 0 ? -d : d;
          float mm = (d <= 3) ? 0.0f
                              : xr[1][r][0] * xc2[c][0] + xr[1][r][1] * xc2[c][1] +
                                    xr[1][r][2] * xc2[c][2] + xr[1][r][3] * xc2[c][3];
          float mhq = 0.5f * mm;
          mv2[k][q] = mhq;
          float aT = ahat_of(upT);
          float a = av2[k][q];
          rs += (a * a + aT * aT) * mhq;
        }
        rs += __shfl_xor(rs, 1); rs += __shfl_xor(rs, 2);
        rs += __shfl_xor(rs, 4); rs += __shfl_xor(rs, 8);
        if (tx == 0) st_agent(&rsp0[(b * NT + C2) * LL + i], rs + 1.0f);
      }
    }
  }

  float (*T1)[TT + 1] = dg ? t1 : t2;
  float (*T2)[TT + 1] = dg ? t2 : t1;

  float alpha = 0.01f;
  float beta_prev = 0.0f;

  for (int t = 0; t < TS; ++t) {
    if (tid < 128) {
      const float* rp = rsp + (size_t)t * RSPSTEP + b * NT * LL + lrow;
      float v0, v1, v2, v3, v4, v5, v6, v7;
      for (;;) {
        v0 = ld_agent(rp + 0 * LL); v1 = ld_agent(rp + 1 * LL);
        v2 = ld_agent(rp + 2 * LL); v3 = ld_agent(rp + 3 * LL);
        v4 = ld_agent(rp + 4 * LL); v5 = ld_agent(rp + 5 * LL);
        v6 = ld_agent(rp + 6 * LL); v7 = ld_agent(rp + 7 * LL);
        bool ok = (v0 != 0.0f) & (v1 != 0.0f) & (v2 != 0.0f) & (v3 != 0.0f) &
                  (v4 != 0.0f) & (v5 != 0.0f) & (v6 != 0.0f) & (v7 != 0.0f);
        if (__all(ok)) break;
        __builtin_amdgcn_s_sleep(2);
        asm volatile("" ::: "memory");
      }
      float rsv = ((v0 + v1) + (v2 + v3)) + ((v4 + v5) + (v6 + v7));
      float dv = rsv - 9.0f;
      float rel = dv > 0.0f ? dv : 0.0f;
      lmbd = (t == 0) ? rel : lmbd + beta_prev * rel;
      float cv2 = 2.0f * (lmbd * sgm(2.0f * dv));
      if (tid >= 64) cJ[tid & 63] = cv2; else cI[tid] = cv2;
    }
    bar_lds();

    float thr = alpha * 0.99f;
    float* cc1 = dg ? cI : cJ;
    float* cc2 = dg ? cJ : cI;

    float cq1[4], cq2[4];
#pragma unroll
    for (int q = 0; q < 4; ++q) {
      cq1[q] = cc1[4 * tx + q];
      cq2[q] = cc2[4 * tx + q];
    }

    float cp1[4] = {0.f, 0.f, 0.f, 0.f};
    float cp2[4] = {0.f, 0.f, 0.f, 0.f};
#pragma unroll
    for (int k = 0; k < 4; ++k) {
      int r = ty + 16 * k;
      {
        float ci = cI[r];
        float rsv = 0.0f;
#pragma unroll
        for (int q = 0; q < 4; ++q) {
          int c = 4 * tx + q;
          float a = av1[k][q];
          float m5 = mv1[k][q];
          float s2 = wv1[k][q] + ci + cq1[q];
          float an = a * fmaf(-alpha, m5 * s2, 1.0f);
          float f = fabsf(an) - thr;
          an = fminf(fmaxf(f, 0.0f), 1.0f);
          av1[k][q] = an;
          float v = an * an * m5;
          t1[r][c] = v;
          rsv += v;
          cp1[q] += v;
        }
        rsv += __shfl_xor(rsv, 1); rsv += __shfl_xor(rsv, 2);
        rsv += __shfl_xor(rsv, 4); rsv += __shfl_xor(rsv, 8);
        if (tx == 0) rp1[r] = rsv;
      }
      {
        float ci = cJ[r];
        float rsv = 0.0f;
#pragma unroll
        for (int q = 0; q < 4; ++q) {
          int c = 4 * tx + q;
          float a = av2[k][q];
          float m5 = mv2[k][q];
          float s2 = wv2[k][q] + ci + cq2[q];
          float an = a * fmaf(-alpha, m5 * s2, 1.0f);
          float f = fabsf(an) - thr;
          an = fminf(fmaxf(f, 0.0f), 1.0f);
          av2[k][q] = an;
          float v = an * an * m5;
          t2[r][c] = v;
          rsv += v;
          cp2[q] += v;
        }
        rsv += __shfl_xor(rsv, 1); rsv += __shfl_xor(rsv, 2);
        rsv += __shfl_xor(rsv, 4); rsv += __shfl_xor(rsv, 8);
        if (tx == 0) rp2[r] = rsv;
      }
    }
#pragma unroll
    for (int q = 0; q < 4; ++q) {
      colp1[ty][4 * tx + q] = cp1[q];
      colp2[ty][4 * tx + q] = cp2[q];
    }
    bar_lds();

    if (tid < 128) {
      if (t < TS - 1) {
        float* rs_next = rsp + (size_t)(t + 1) * RSPSTEP;
        if (tid < 64) {
          int i = tid;
          float vsum = rp1[i];
          float (*cpA)[TT] = dg ? colp1 : colp2;
#pragma unroll
          for (int y = 0; y < 16; ++y) vsum += cpA[y][i];
          st_agent(&rs_next[(b * NT + C1) * LL + RI * TT + i], vsum + 1.0f);
        } else {
          int i = tid - 64;
          float vsum = rp2[i];
          float (*cpB)[TT] = dg ? colp2 : colp1;
#pragma unroll
          for (int y = 0; y < 16; ++y) vsum += cpB[y][i];
          st_agent(&rs_next[(b * NT + C2) * LL + RJ * TT + i], vsum + 1.0f);
        }
      }
    } else {
      int tid2 = tid - 128;
      int tx2 = tid2 & 15, ty2 = tid2 >> 4;
      float* op = out + (size_t)t * BLL;
#pragma unroll
      for (int k = 0; k < 8; ++k) {
        int r = ty2 + 8 * k;
        {
          int off = (b * LL + RI * TT + r) * LL + C1 * TT + 4 * tx2;
          float4n res;
#pragma unroll
          for (int q = 0; q < 4; ++q) res[q] = t1[r][4 * tx2 + q] + T1[4 * tx2 + q][r];
          __builtin_nontemporal_store(res, reinterpret_cast<float4n*>(op + off));
        }
        {
          int off = (b * LL + RJ * TT + r) * LL + C2 * TT + 4 * tx2;
          float4n res;
#pragma unroll
          for (int q = 0; q < 4; ++q) res[q] = t2[r][4 * tx2 + q] + T2[4 * tx2 + q][r];
          __builtin_nontemporal_store(res, reinterpret_cast<float4n*>(op + off));
        }
      }
    }

    beta_prev = (t == 0) ? 0.1f : beta_prev * 0.99f;
    alpha *= 0.99f;
  }
}

// =====================================================================
// FALLBACK 2: verbatim multi-kernel path (proven correct, 603 us).
// =====================================================================
__device__ __forceinline__ void decode_pair(int p, int& I, int& J) {
  int base = 0, i = 0;
  while (p >= base + (NT - i)) { base += NT - i; ++i; }
  I = i;
  J = i + (p - base);
}

__global__ __launch_bounds__(256) void k_init(const float* __restrict__ u,
                                              const float* __restrict__ x,
                                              float* __restrict__ w,
                                              float* __restrict__ ah,
                                              float* __restrict__ rowsum) {
  __shared__ float up1[TT][TT + 1];
  __shared__ float up2[TT][TT + 1];
  __shared__ float xr[2][TT][4];
  __shared__ float xt[2][TT][4];

  int b = blockIdx.x / NPAIR;
  int p = blockIdx.x % NPAIR;
  int I, J;
  decode_pair(p, I, J);
  bool diag = (I == J);
  int tid = threadIdx.x;
  int tx = tid & 15, ty = tid >> 4;

  if (tid < 128) {
    int which = tid >> 6;
    int r = tid & 63;
    int gi = (which ? J : I) * TT + r;
    const float* xp = x + ((b * LL) + gi) * 4;
    float A = xp[0], U = xp[1], C = xp[2], G = xp[3];
    xr[which][r][0] = A; xr[which][r][1] = U; xr[which][r][2] = C; xr[which][r][3] = G;
    xt[which][r][0] = U; xt[which][r][1] = A + G; xt[which][r][2] = G; xt[which][r][3] = C + U;
  }

  float a1r[4][4], a2r[4][4];

#pragma unroll
  for (int k = 0; k < 4; ++k) {
    int r = ty + 16 * k;
    {
      int i = I * TT + r;
      int off = (b * LL + i) * LL + J * TT + 4 * tx;
      float4 u4 = *reinterpret_cast<const float4*>(u + off);
      float uu[4] = {u4.x, u4.y, u4.z, u4.w};
      float av[4];
#pragma unroll
      for (int q = 0; q < 4; ++q) {
        float up = sgm(2.0f * (uu[q] - S_CONST)) * uu[q];
        up1[r][4 * tx + q] = up;
        av[q] = ahat_of(up);
        a1r[k][q] = av[q];
      }
      *reinterpret_cast<float4*>(ah + off) = make_float4(av[0], av[1], av[2], av[3]);
    }
    if (!diag) {
      int i = J * TT + r;
      int off = (b * LL + i) * LL + I * TT + 4 * tx;
      float4 u4 = *reinterpret_cast<const float4*>(u + off);
      float uu[4] = {u4.x, u4.y, u4.z, u4.w};
      float av[4];
#pragma unroll
      for (int q = 0; q < 4; ++q) {
        float up = sgm(2.0f * (uu[q] - S_CONST)) * uu[q];
        up2[r][4 * tx + q] = up;
        av[q] = ahat_of(up);
        a2r[k][q] = av[q];
      }
      *reinterpret_cast<float4*>(ah + off) = make_float4(av[0], av[1], av[2], av[3]);
    }
  }
  __syncthreads();

  float (*U2)[TT + 1] = diag ? up1 : up2;

#pragma unroll
  for (int k = 0; k < 4; ++k) {
    int r = ty + 16 * k;
    {
      int i = I * TT + r;
      int off = (b * LL + i) * LL + J * TT + 4 * tx;
      float wv[4];
      float rs = 0.0f;
#pragma unroll
      for (int q = 0; q < 4; ++q) {
        int c = 4 * tx + q;
        int j = J * TT + c;
        float upT = U2[c][r];
        wv[q] = -0.5f * (up1[r][c] + upT);
        int d = i - j; d = d < 0 ? -d : d;
        float mm = (d <= 3) ? 0.0f
                            : xr[0][r][0] * xt[1][c][0] + xr[0][r][1] * xt[1][c][1] +
                                  xr[0][r][2] * xt[1][c][2] + xr[0][r][3] * xt[1][c][3];
        float aT = ahat_of(upT);
        float a = a1r[k][q];
        rs += 0.5f * (a * a + aT * aT) * mm;
      }
      *reinterpret_cast<float4*>(w + off) = make_float4(wv[0], wv[1], wv[2], wv[3]);
      rs += __shfl_xor(rs, 1); rs += __shfl_xor(rs, 2);
      rs += __shfl_xor(rs, 4); rs += __shfl_xor(rs, 8);
      if (tx == 0) atomicAdd(&rowsum[b * LL + i], rs);
    }
    if (!diag) {
      int i = J * TT + r;
      int off = (b * LL + i) * LL + I * TT + 4 * tx;
      float wv[4];
      float rs = 0.0f;
#pragma unroll
      for (int q = 0; q < 4; ++q) {
        int c = 4 * tx + q;
        int j = I * TT + c;
        float upT = up1[c][r];
        wv[q] = -0.5f * (up2[r][c] + upT);
        int d = i - j; d = d < 0 ? -d : d;
        float mm = (d <= 3) ? 0.0f
                            : xr[1][r][0] * xt[0][c][0] + xr[1][r][1] * xt[0][c][1] +
                                  xr[1][r][2] * xt[0][c][2] + xr[1][r][3] * xt[0][c][3];
        float aT = ahat_of(upT);
        float a = a2r[k][q];
        rs += 0.5f * (a * a + aT * aT) * mm;
      }
      *reinterpret_cast<float4*>(w + off) = make_float4(wv[0], wv[1], wv[2], wv[3]);
      rs += __shfl_xor(rs, 1); rs += __shfl_xor(rs, 2);
      rs += __shfl_xor(rs, 4); rs += __shfl_xor(rs, 8);
      if (tx == 0) atomicAdd(&rowsum[b * LL + i], rs);
    }
  }
}

__global__ __launch_bounds__(256) void k_c(float* __restrict__ lmbd,
                                           const float* __restrict__ rs,
                                           float* __restrict__ cc,
                                           float* __restrict__ rsn,
                                           float beta_prev, int first) {
  int idx = blockIdx.x * blockDim.x + threadIdx.x;
  if (idx >= NROW) return;
  float t = rs[idx] - 1.0f;
  float rel = t > 0.0f ? t : 0.0f;
  float l = first ? rel : lmbd[idx] + beta_prev * rel;
  lmbd[idx] = l;
  cc[idx] = l * sgm(2.0f * t);
  rsn[idx] = 0.0f;
}

__global__ __launch_bounds__(256) void k_step(const float* __restrict__ x,
                                              const float* __restrict__ w,
                                              float* __restrict__ ah,
                                              const float* __restrict__ cvec,
                                              float* __restrict__ rsn,
                                              float* __restrict__ out,
                                              float alpha, float thr) {
  __shared__ float an1[TT][TT + 1];
  __shared__ float an2[TT][TT + 1];
  __shared__ float xr[2][TT][4];
  __shared__ float xt[2][TT][4];
  __shared__ float cI[TT];
  __shared__ float cJ[TT];

  int b = blockIdx.x / NPAIR;
  int p = blockIdx.x % NPAIR;
  int I, J;
  decode_pair(p, I, J);
  bool diag = (I == J);
  int tid = threadIdx.x;
  int tx = tid & 15, ty = tid >> 4;

  if (tid < 128) {
    int which = tid >> 6;
    int r = tid & 63;
    int gi = (which ? J : I) * TT + r;
    const float* xp = x + ((b * LL) + gi) * 4;
    float A = xp[0], U = xp[1], C = xp[2], G = xp[3];
    xr[which][r][0] = A; xr[which][r][1] = U; xr[which][r][2] = C; xr[which][r][3] = G;
    xt[which][r][0] = U; xt[which][r][1] = A + G; xt[which][r][2] = G; xt[which][r][3] = C + U;
  } else {
    int t2i = tid - 128;
    int which = t2i >> 6;
    int r = t2i & 63;
    int gi = (which ? J : I) * TT + r;
    float cv = cvec[b * LL + gi];
    if (which) cJ[r] = cv; else cI[r] = cv;
  }
  __syncthreads();

  float m1[4][4], m2[4][4];

#pragma unroll
  for (int k = 0; k < 4; ++k) {
    int r = ty + 16 * k;
    {
      int i = I * TT + r;
      int off = (b * LL + i) * LL + J * TT + 4 * tx;
      float4 a4 = *reinterpret_cast<const float4*>(ah + off);
      float4 w4 = *reinterpret_cast<const float4*>(w + off);
      float av[4] = {a4.x, a4.y, a4.z, a4.w};
      float wv[4] = {w4.x, w4.y, w4.z, w4.w};
      float ci = cI[r];
      float res[4];
#pragma unroll
      for (int q = 0; q < 4; ++q) {
        int c = 4 * tx + q;
        int j = J * TT + c;
        int d = i - j; d = d < 0 ? -d : d;
        float mm = (d <= 3) ? 0.0f
                            : xr[0][r][0] * xt[1][c][0] + xr[0][r][1] * xt[1][c][1] +
                                  xr[0][r][2] * xt[1][c][2] + xr[0][r][3] * xt[1][c][3];
        m1[k][q] = mm;
        float g = av[q] * mm * (wv[q] + ci + cJ[c]);
        float an = av[q] - alpha * g;
        an = fabsf(an) - thr;
        an = an > 0.0f ? an : 0.0f;
        an = an < 1.0f ? an : 1.0f;
        res[q] = an;
        an1[r][c] = an;
      }
      *reinterpret_cast<float4*>(ah + off) = make_float4(res[0], res[1], res[2], res[3]);
    }
    if (!diag) {
      int i = J * TT + r;
      int off = (b * LL + i) * LL + I * TT + 4 * tx;
      float4 a4 = *reinterpret_cast<const float4*>(ah + off);
      float4 w4 = *reinterpret_cast<const float4*>(w + off);
      float av[4] = {a4.x, a4.y, a4.z, a4.w};
      float wv[4] = {w4.x, w4.y, w4.z, w4.w};
      float ci = cJ[r];
      float res[4];
#pragma unroll
      for (int q = 0; q < 4; ++q) {
        int c = 4 * tx + q;
        int j = I * TT + c;
        int d = i - j; d = d < 0 ? -d : d;
        float mm = (d <= 3) ? 0.0f
                            : xr[1][r][0] * xt[0][c][0] + xr[1][r][1] * xt[0][c][1] +
                                  xr[1][r][2] * xt[0][c][2] + xr[1][r][3] * xt[0][c][3];
        m2[k][q] = mm;
        float g = av[q] * mm * (wv[q] + ci + cI[c]);
        float an = av[q] - alpha * g;
        an = fabsf(an) - thr;
        an = an > 0.0f ? an : 0.0f;
        an = an < 1.0f ? an : 1.0f;
        res[q] = an;
        an2[r][c] = an;
      }
      *reinterpret_cast<float4*>(ah + off) = make_float4(res[0], res[1], res[2], res[3]);
    }
  }
  __syncthreads();

  float (*A2)[TT + 1] = diag ? an1 : an2;

#pragma unroll
  for (int k = 0; k < 4; ++k) {
    int r = ty + 16 * k;
    {
      int i = I * TT + r;
      int off = (b * LL + i) * LL + J * TT + 4 * tx;
      float res[4];
      float rs = 0.0f;
#pragma unroll
      for (int q = 0; q < 4; ++q) {
        int c = 4 * tx + q;
        float a = an1[r][c];
        float bt = A2[c][r];
        float v = 0.5f * (a * a + bt * bt) * m1[k][q];
        res[q] = v;
        rs += v;
      }
      *reinterpret_cast<float4*>(out + off) = make_float4(res[0], res[1], res[2], res[3]);
      rs += __shfl_xor(rs, 1); rs += __shfl_xor(rs, 2);
      rs += __shfl_xor(rs, 4); rs += __shfl_xor(rs, 8);
      if (tx == 0) atomicAdd(&rsn[b * LL + i], rs);
    }
    if (!diag) {
      int i = J * TT + r;
      int off = (b * LL + i) * LL + I * TT + 4 * tx;
      float res[4];
      float rs = 0.0f;
#pragma unroll
      for (int q = 0; q < 4; ++q) {
        int c = 4 * tx + q;
        float a = an2[r][c];
        float bt = an1[c][r];
        float v = 0.5f * (a * a + bt * bt) * m2[k][q];
        res[q] = v;
        rs += v;
      }
      *reinterpret_cast<float4*>(out + off) = make_float4(res[0], res[1], res[2], res[3]);
      rs += __shfl_xor(rs, 1); rs += __shfl_xor(rs, 2);
      rs += __shfl_xor(rs, 4); rs += __shfl_xor(rs, 8);
      if (tx == 0) atomicAdd(&rsn[b * LL + i], rs);
    }
  }
}

// ---------------------------------------------------------------------------
extern "C" void kernel_launch(void* const* d_in, const int* in_sizes, int n_in,
                              void* d_out, int out_size, void* d_ws, size_t ws_size,
                              hipStream_t stream) {
  const float* u = (const float*)d_in[0];
  const float* x = (const float*)d_in[1];
  float* out = (float*)d_out;
  float* ws = (float*)d_ws;

  // ---- round-8 panel path: workspace = cbuf only (~690 KB) ----
  if (ws_size >= (size_t)(1 << 20)) {
    hipError_t attrErr = hipFuncSetAttribute(
        (const void*)k_panel, hipFuncAttributeMaxDynamicSharedMemorySize, SM2_BYTES);
    if (attrErr == hipSuccess) {
      float* cbuf = ws;
      (void)hipMemsetAsync(cbuf, 0, (size_t)(TS + 1) * CROWS * sizeof(float), stream);
      void* argsP[] = {(void*)&u, (void*)&x, (void*)&cbuf, (void*)&out};
      hipError_t errP = hipLaunchCooperativeKernel((void*)k_panel, dim3(NBLK2),
                                                   dim3(256), argsP, SM2_BYTES, stream);
      if (errP == hipSuccess) return;
    }
  }

  // ---- fallback 1: round-5 pair-tile cooperative kernel ----
  float* rsp = ws;
  (void)hipMemsetAsync(rsp, 0, (size_t)TS * RSPSTEP * sizeof(float), stream);
  void* args[] = {(void*)&u, (void*)&x, (void*)&rsp, (void*)&out};
  hipError_t err = hipLaunchCooperativeKernel((void*)k_fused, dim3(NBLK), dim3(256),
                                              args, 0, stream);
  if (err == hipSuccess) return;

  // ---- fallback 2: proven multi-kernel path ----
  float* w = ws;
  float* ah = ws + (size_t)BLL;
  float* rsA = ws + 2 * (size_t)BLL;
  float* rsB = rsA + NROW;
  float* cc = rsB + NROW;
  float* lmbd = cc + NROW;

  (void)hipMemsetAsync(rsA, 0, NROW * sizeof(float), stream);

  dim3 grid(BB * NPAIR);
  dim3 block(256);
  k_init<<<grid, block, 0, stream>>>(u, x, w, ah, rsA);

  float* ra = rsA;
  float* rb = rsB;
  for (int t = 0; t < TS; ++t) {
    float alpha = 0.01f * powf(0.99f, (float)t);
    float beta_prev = (t > 0) ? 0.1f * powf(0.99f, (float)(t - 1)) : 0.0f;
    k_c<<<dim3((NROW + 255) / 256), block, 0, stream>>>(lmbd, ra, cc, rb, beta_prev,
                                                        t == 0 ? 1 : 0);
    k_step<<<grid, block, 0, stream>>>(x, w, ah, cc, rb, out + (size_t)t * BLL, alpha,
                                       alpha * 0.99f);
    float* tmp = ra; ra = rb; rb = tmp;
  }
}